// Round 3
// baseline (518.862 us; speedup 1.0000x reference)
//
#include <hip/hip_runtime.h>
#include <stdint.h>

// Problem: B=16, S=512, H=2048, NH=16, NKV=4, HD=128
// out = Wo-proj( softmax(rope(q) @ rope(k)^T * hd^-.5) @ v )  with GQA rep=4
//
// ws layout (f16 intermediates):
//   x_h   [8192,2048]        @ 0
//   w_h   [3072,2048]        @ 33554432  (Wq 0..2047, Wk 2048..2559, Wv 2560..3071)
//   wo_h  [2048,2048]        @ 46137344
//   q     [16,16,512,128]    @ 54525952   (RoPE fused in gemm epilogue)
//   k     [16,4,512,128]     @ 88080384   (RoPE fused)
//   vt    [16,4,128,512]     @ 96468992   (V transposed)
//   attn  [8192,2048]        @ 104857600

typedef _Float16 f16;
typedef _Float16 f16x4 __attribute__((ext_vector_type(4)));
typedef _Float16 f16x8 __attribute__((ext_vector_type(8)));
typedef float f32x4 __attribute__((ext_vector_type(4)));

#define B_   16
#define S_   512
#define H_   2048
#define NH_  16
#define NKV_ 4
#define HD_  128
#define ATT_SCALE 0.08838834764831843f
#define LOG2_10000_DIV64 0.20762050593045952f

#define AS1 __attribute__((address_space(1)))
#define AS3 __attribute__((address_space(3)))

// async global->LDS, 16B/lane. LDS dest must be wave-uniform; HW adds lane*16.
__device__ __forceinline__ void async16(const void* g, const void* l) {
  __builtin_amdgcn_global_load_lds((const AS1 unsigned int*)(uintptr_t)g,
                                   (AS3 unsigned int*)(uintptr_t)l, 16, 0, 0);
}

// ---------------- fused fp32 -> f16 cast for all 5 inputs ----------------
__global__ __launch_bounds__(256) void cast_all(const float* __restrict__ x,
                                                const float* __restrict__ wq,
                                                const float* __restrict__ wk,
                                                const float* __restrict__ wv,
                                                const float* __restrict__ wo,
                                                f16* __restrict__ x_h,
                                                f16* __restrict__ w_h,
                                                f16* __restrict__ wo_h) {
  const int i = blockIdx.x * 256 + threadIdx.x;
  const float4* src;
  f16x4* dst;
  if (i < 4194304) {                 // x: 8192*2048
    src = (const float4*)x + i;            dst = (f16x4*)x_h + i;
  } else if (i < 5242880) {          // Wq: 2048*2048
    int j = i - 4194304;
    src = (const float4*)wq + j;           dst = (f16x4*)w_h + j;
  } else if (i < 5505024) {          // Wk: 512*2048
    int j = i - 5242880;
    src = (const float4*)wk + j;           dst = (f16x4*)w_h + 1048576 + j;
  } else if (i < 5767168) {          // Wv: 512*2048
    int j = i - 5505024;
    src = (const float4*)wv + j;           dst = (f16x4*)w_h + 1310720 + j;
  } else {                           // Wo: 2048*2048
    int j = i - 5767168;
    src = (const float4*)wo + j;           dst = (f16x4*)wo_h + j;
  }
  float4 v = *src;
  f16x4 o = {(f16)v.x, (f16)v.y, (f16)v.z, (f16)v.w};
  *dst = o;
}

// ---------------- 256x128 GEMM, BK=64, 8 waves, 3-deep LDS ring ----------
// (unchanged from previous round: ring-3, counted vmcnt, swizzled frag reads)
template<int MODE>
__global__ __launch_bounds__(512, 2) void gemm_k(const f16* __restrict__ A,
                                                 const f16* __restrict__ W,
                                                 f16* __restrict__ qo,
                                                 f16* __restrict__ ko,
                                                 f16* __restrict__ vto,
                                                 float* __restrict__ fout) {
  __shared__ __align__(16) f16 As[3][256 * 64];   // 3 x 32 KiB
  __shared__ __align__(16) f16 Bs[3][128 * 64];   // 3 x 16 KiB  (total 144 KiB)
  const int K = 2048;
  const int NT = 32;                       // K / 64
  const int m0 = blockIdx.x * 256;
  const int n0 = blockIdx.y * 128;
  const int tid = threadIdx.x;
  const int wave = tid >> 6, lane = tid & 63;
  const int quad = lane >> 4, l15 = lane & 15;
  const int wm = wave >> 1, wn = wave & 1;  // 4M x 2N, 64x64 per wave

  const f16* aptr[4];
  const f16* bptr[2];
#pragma unroll
  for (int i = 0; i < 4; ++i) {
    const int L = i * 512 + wave * 64 + lane;
    const int r = L >> 3, s = L & 7;
    aptr[i] = A + (size_t)(m0 + r) * K + (s ^ (r & 7)) * 8;
  }
#pragma unroll
  for (int i = 0; i < 2; ++i) {
    const int L = i * 512 + wave * 64 + lane;
    const int r = L >> 3, s = L & 7;
    bptr[i] = W + (size_t)(n0 + r) * K + (s ^ (r & 7)) * 8;
  }
  const int ldsw = wave * 1024;            // wave's chunk-group byte base

  f32x4 acc[4][4] = {};
  f16x8 aC[4], bC[4], aN[4], bN[4];

  auto ldA = [&](f16x8* d, const f16* base, int ks) {
#pragma unroll
    for (int mi = 0; mi < 4; ++mi) {
      const int row = wm * 64 + mi * 16 + l15;
      const int slot = (ks * 4 + quad) ^ (l15 & 7);
      d[mi] = *reinterpret_cast<const f16x8*>(base + row * 64 + slot * 8);
    }
  };
  auto ldB = [&](f16x8* d, const f16* base, int ks) {
#pragma unroll
    for (int ni = 0; ni < 4; ++ni) {
      const int col = wn * 32 + (ni >> 1) * 64 + (ni & 1) * 16 + l15;
      const int slot = (ks * 4 + quad) ^ (l15 & 7);
      d[ni] = *reinterpret_cast<const f16x8*>(base + col * 64 + slot * 8);
    }
  };
  auto mfma16 = [&](const f16x8* Af, const f16x8* Bf) {
#pragma unroll
    for (int mi = 0; mi < 4; ++mi)
#pragma unroll
      for (int ni = 0; ni < 4; ++ni)
        acc[mi][ni] = __builtin_amdgcn_mfma_f32_16x16x32_f16(Af[mi], Bf[ni], acc[mi][ni], 0, 0, 0);
  };

  // prologue: stage tiles 0,1 (12 loads/thread)
#pragma unroll
  for (int t = 0; t < 2; ++t) {
#pragma unroll
    for (int i = 0; i < 4; ++i)
      async16(aptr[i] + t * 64, (const char*)&As[t][0] + i * 8192 + ldsw);
#pragma unroll
    for (int i = 0; i < 2; ++i)
      async16(bptr[i] + t * 64, (const char*)&Bs[t][0] + i * 8192 + ldsw);
  }
  asm volatile("s_waitcnt vmcnt(6)" ::: "memory");  // tile 0 landed
  __builtin_amdgcn_s_barrier();
  ldA(aC, &As[0][0], 0);
  ldB(bC, &Bs[0][0], 0);

  for (int t = 0; t < NT; ++t) {
    const int buf = t % 3, bufn = (t + 1) % 3, bufs = (t + 2) % 3;
    const int sk = (t + 2) * 64;

    // ---- P0: MFMA ks=0 while ks=1 reads + 3 stage loads are in flight ----
    ldA(aN, &As[buf][0], 1);
    ldB(bN, &Bs[buf][0], 1);
    if (t + 2 < NT) {
      async16(aptr[0] + sk, (const char*)&As[bufs][0] + 0 * 8192 + ldsw);
      async16(aptr[1] + sk, (const char*)&As[bufs][0] + 1 * 8192 + ldsw);
      async16(bptr[0] + sk, (const char*)&Bs[bufs][0] + 0 * 8192 + ldsw);
    }
    asm volatile("s_waitcnt lgkmcnt(8)" ::: "memory");  // aC/bC ready
    __builtin_amdgcn_sched_barrier(0);
    __builtin_amdgcn_s_setprio(1);
    mfma16(aC, bC);
    __builtin_amdgcn_s_setprio(0);

    // ---- MID: tile t+1 resident (counted vmcnt, all waves) ----
    if (t + 1 < NT) {
      if (t + 2 < NT) asm volatile("s_waitcnt vmcnt(3)" ::: "memory");
      else            asm volatile("s_waitcnt vmcnt(0)" ::: "memory");
      __builtin_amdgcn_s_barrier();
    }

    // ---- P1: MFMA ks=1 while next-tile ks=0 reads + 3 stages in flight ----
    if (t + 1 < NT) {
      ldA(aC, &As[bufn][0], 0);
      ldB(bC, &Bs[bufn][0], 0);
    }
    if (t + 2 < NT) {
      async16(aptr[2] + sk, (const char*)&As[bufs][0] + 2 * 8192 + ldsw);
      async16(aptr[3] + sk, (const char*)&As[bufs][0] + 3 * 8192 + ldsw);
      async16(bptr[1] + sk, (const char*)&Bs[bufs][0] + 1 * 8192 + ldsw);
    }
    if (t + 1 < NT) asm volatile("s_waitcnt lgkmcnt(8)" ::: "memory");
    else            asm volatile("s_waitcnt lgkmcnt(0)" ::: "memory");
    __builtin_amdgcn_sched_barrier(0);
    __builtin_amdgcn_s_setprio(1);
    mfma16(aN, bN);
    __builtin_amdgcn_s_setprio(0);
    if (t + 1 < NT) __builtin_amdgcn_s_barrier();
  }

  // ---------------- epilogues ----------------
  if constexpr (MODE == 1) {
    const int b_ = m0 >> 9;  // batch (uniform per block; 256 | 512)
    if (n0 >= 2560) {
      // ---- V: no rope, store transposed [b, kh, d, s] ----
      const int h = (n0 - 2560) >> 7;
      f16* vb = vto + ((size_t)b_ * NKV_ + h) * HD_ * S_;
#pragma unroll
      for (int mi = 0; mi < 4; ++mi)
#pragma unroll
        for (int r = 0; r < 4; ++r) {
          const int s = (m0 + wm * 64 + mi * 16 + quad * 4 + r) & 511;
#pragma unroll
          for (int ni = 0; ni < 4; ++ni) {
            const int d = (ni >> 1) * 64 + wn * 32 + (ni & 1) * 16 + l15;
            vb[(size_t)d * S_ + s] = (f16)acc[mi][ni][r];
          }
        }
    } else {
      // ---- Q or K: fused RoPE, store [b, h, s, d] ----
      f16* ob = (n0 < 2048)
          ? (qo + ((size_t)b_ * NH_ + (n0 >> 7)) * S_ * HD_)
          : (ko + ((size_t)b_ * NKV_ + ((n0 - 2048) >> 7)) * S_ * HD_);
      float invf[2];
#pragma unroll
      for (int ni = 0; ni < 2; ++ni)
        invf[ni] = exp2f((float)(wn * 32 + ni * 16 + l15) * -LOG2_10000_DIV64);
#pragma unroll
      for (int mi = 0; mi < 4; ++mi)
#pragma unroll
        for (int r = 0; r < 4; ++r) {
          const int s = (m0 + wm * 64 + mi * 16 + quad * 4 + r) & 511;
          const size_t rb = (size_t)s * HD_;
#pragma unroll
          for (int ni = 0; ni < 2; ++ni) {
            const int d = wn * 32 + ni * 16 + l15;  // 0..63
            float sn, cs;
            __sincosf((float)s * invf[ni], &sn, &cs);
            const float x1 = acc[mi][ni][r], x2 = acc[mi][ni + 2][r];
            ob[rb + d] = (f16)(x1 * cs - x2 * sn);
            ob[rb + d + 64] = (f16)(x2 * cs + x1 * sn);
          }
        }
    }
  } else {
    // ---- fp32 output: out = attn @ Wo^T ----
#pragma unroll
    for (int mi = 0; mi < 4; ++mi)
#pragma unroll
      for (int ni = 0; ni < 4; ++ni) {
        const int ncol = n0 + wn * 32 + (ni >> 1) * 64 + (ni & 1) * 16 + l15;
#pragma unroll
        for (int r = 0; r < 4; ++r) {
          const int mrow = m0 + wm * 64 + mi * 16 + quad * 4 + r;
          fout[(size_t)mrow * 2048 + ncol] = acc[mi][ni][r];
        }
      }
  }
}

// ---------------- flash attention (v3) ----------------
// 8 waves x 32 q-rows = 256 rows/block, grid (2,16,16)=512 blocks.
// KVBLK=64, K double-buffered in LDS, V single-buffered, Q in registers.
// LDS = 80 KiB -> 2 blocks/CU: all 512 blocks co-resident (one round),
// cross-block overlap hides staging latency. Raw s_barrier + own-loads-
// drained-before-barrier ordering (no __syncthreads vmcnt(0) drain of the
// in-flight K[j+1] prefetch).
// LDS reads/wave/j: 16 bk + 4 ap + 16 bv (each V frag read once: ks-outer,
// ni-inner, both mi share bv). Ps XOR-swizzled stride-64 (no pad).
__global__ __launch_bounds__(512, 4) void attn_kernel(const f16* __restrict__ q,
                                                      const f16* __restrict__ k,
                                                      const f16* __restrict__ vt,
                                                      f16* __restrict__ out) {
  __shared__ __align__(16) f16 Kb[2][64 * 128];   // [key][d], chunk c^(r&15)
  __shared__ __align__(16) f16 Vb[128 * 64];      // [d][key], chunk c^(r&7)
  __shared__ __align__(16) f16 Ps[8][32 * 64];    // per-wave P, chunk c^(r&7)

  const int qt = blockIdx.x, h = blockIdx.y, b = blockIdx.z;
  const int kvh = h >> 2;
  const int tid = threadIdx.x;
  const int wave = tid >> 6, lane = tid & 63;
  const int quad = lane >> 4, l15 = lane & 15;

  const f16* qbase = q + (((size_t)b * NH_ + h) * S_ + qt * 256) * HD_;
  const f16* kbase = k + ((size_t)b * NKV_ + kvh) * S_ * HD_;
  const f16* vbase = vt + ((size_t)b * NKV_ + kvh) * HD_ * S_;

  auto stageK = [&](int j) {
    f16* dst = &Kb[j & 1][0];
#pragma unroll
    for (int i = 0; i < 2; ++i) {
      const int L0 = i * 512 + wave * 64;          // wave-uniform base chunk
      const int L = L0 + lane;
      const int r = L >> 4, c = L & 15;
      async16(kbase + (size_t)(j * 64 + r) * HD_ + (c ^ (r & 15)) * 8,
              (const char*)dst + (size_t)L0 * 16);
    }
  };
  auto stageV = [&](int j) {
#pragma unroll
    for (int i = 0; i < 2; ++i) {
      const int L0 = i * 512 + wave * 64;
      const int L = L0 + lane;
      const int r = L >> 3, c = L & 7;
      async16(vbase + (size_t)r * S_ + j * 64 + (c ^ (r & 7)) * 8,
              (const char*)&Vb[0] + (size_t)L0 * 16);
    }
  };

  // Q fragments straight to registers (read exactly once, union covers tile)
  f16x8 aq[2][4];
#pragma unroll
  for (int mi = 0; mi < 2; ++mi)
#pragma unroll
    for (int ks = 0; ks < 4; ++ks)
      aq[mi][ks] = *reinterpret_cast<const f16x8*>(
          qbase + (size_t)(wave * 32 + mi * 16 + l15) * HD_ + ks * 32 + quad * 8);

  stageK(0);

  f32x4 O[2][8] = {};
  float mrun[2][4], lrun[2][4];
#pragma unroll
  for (int mi = 0; mi < 2; ++mi)
#pragma unroll
    for (int r = 0; r < 4; ++r) { mrun[mi][r] = -3.0e38f; lrun[mi][r] = 0.f; }

  for (int j = 0; j < 8; ++j) {
    // K[j] is the only outstanding group (plus aq at j=0): drain own, then
    // barrier -> every wave's staging portion visible to all.
    asm volatile("s_waitcnt vmcnt(0)" ::: "memory");
    __builtin_amdgcn_s_barrier();           // also: all waves done PV[j-1]
    stageV(j);                               // hides under QK^T + softmax

    // ---- S = Q K^T for 32 q-rows x 64 keys ----
    f32x4 Sc[2][4] = {};
#pragma unroll
    for (int ks = 0; ks < 4; ++ks) {
      f16x8 bk[4];
#pragma unroll
      for (int ni = 0; ni < 4; ++ni) {
        const int row = ni * 16 + l15;
        bk[ni] = *reinterpret_cast<const f16x8*>(
            &Kb[j & 1][row * 128 + (((ks * 4 + quad) ^ l15) & 15) * 8]);
      }
#pragma unroll
      for (int mi = 0; mi < 2; ++mi)
#pragma unroll
        for (int ni = 0; ni < 4; ++ni)
          Sc[mi][ni] = __builtin_amdgcn_mfma_f32_16x16x32_f16(aq[mi][ks], bk[ni], Sc[mi][ni], 0, 0, 0);
    }

    // ---- online softmax (row = mi*16 + quad*4 + r, col = ni*16 + l15) ----
#pragma unroll
    for (int mi = 0; mi < 2; ++mi)
#pragma unroll
      for (int r = 0; r < 4; ++r) {
        float mx = fmaxf(fmaxf(Sc[mi][0][r], Sc[mi][1][r]),
                         fmaxf(Sc[mi][2][r], Sc[mi][3][r]));
        mx *= ATT_SCALE;
#pragma unroll
        for (int off = 1; off < 16; off <<= 1) mx = fmaxf(mx, __shfl_xor(mx, off));
        const float mnew = fmaxf(mrun[mi][r], mx);
        const float alpha = __expf(mrun[mi][r] - mnew);
        float rs = 0.f;
#pragma unroll
        for (int ni = 0; ni < 4; ++ni) {
          const float pv = __expf(Sc[mi][ni][r] * ATT_SCALE - mnew);
          Sc[mi][ni][r] = pv;
          rs += pv;
        }
#pragma unroll
        for (int off = 1; off < 16; off <<= 1) rs += __shfl_xor(rs, off);
        lrun[mi][r] = lrun[mi][r] * alpha + rs;
        mrun[mi][r] = mnew;
#pragma unroll
        for (int ni = 0; ni < 8; ++ni) O[mi][ni][r] *= alpha;
        const int rowl = mi * 16 + quad * 4 + r;
#pragma unroll
        for (int ni = 0; ni < 4; ++ni) {
          const int col = ni * 16 + l15;
          Ps[wave][rowl * 64 + (((ni * 2 + (l15 >> 3)) ^ (rowl & 7)) << 3) + (l15 & 7)] =
              (f16)Sc[mi][ni][r];
        }
      }

    // V[j] landed? (K[j+1] not yet issued -> vmcnt(0) is exact & cheap here)
    asm volatile("s_waitcnt vmcnt(0)" ::: "memory");
    __builtin_amdgcn_s_barrier();           // Vb visible to all waves
    if (j < 7) stageK(j + 1);                // hides under PV + next QK^T

    // ---- O += P V (ks-outer, ni-inner: each bv read once, shared by mi) ----
#pragma unroll
    for (int ks = 0; ks < 2; ++ks) {
      f16x8 ap[2];
#pragma unroll
      for (int mi = 0; mi < 2; ++mi) {
        const int rowl = mi * 16 + l15;
        ap[mi] = *reinterpret_cast<const f16x8*>(
            &Ps[wave][rowl * 64 + (((ks * 4 + quad) ^ (l15 & 7)) << 3)]);
      }
#pragma unroll
      for (int ni = 0; ni < 8; ++ni) {
        const int row = ni * 16 + l15;
        const f16x8 bv = *reinterpret_cast<const f16x8*>(
            &Vb[row * 64 + (((ks * 4 + quad) ^ (l15 & 7)) << 3)]);
#pragma unroll
        for (int mi = 0; mi < 2; ++mi)
          O[mi][ni] = __builtin_amdgcn_mfma_f32_16x16x32_f16(ap[mi], bv, O[mi][ni], 0, 0, 0);
      }
    }
  }

  // epilogue: normalize, write attn[b, s, h*128 + d]
#pragma unroll
  for (int mi = 0; mi < 2; ++mi)
#pragma unroll
    for (int r = 0; r < 4; ++r) {
      const float inv = 1.f / lrun[mi][r];
      const int srow = qt * 256 + wave * 32 + mi * 16 + quad * 4 + r;
#pragma unroll
      for (int ni = 0; ni < 8; ++ni)
        out[((size_t)b * S_ + srow) * H_ + h * HD_ + ni * 16 + l15] = (f16)(O[mi][ni][r] * inv);
    }
}

extern "C" void kernel_launch(void* const* d_in, const int* in_sizes, int n_in,
                              void* d_out, int out_size, void* d_ws, size_t ws_size,
                              hipStream_t stream) {
  const float* x = (const float*)d_in[0];
  const float* Wq = (const float*)d_in[1];
  const float* Wk = (const float*)d_in[2];
  const float* Wv = (const float*)d_in[3];
  const float* Wo = (const float*)d_in[4];
  float* out = (float*)d_out;
  char* ws = (char*)d_ws;

  f16* x_h  = (f16*)(ws + 0);
  f16* w_h  = (f16*)(ws + 33554432);
  f16* wo_h = (f16*)(ws + 46137344);
  f16* qb   = (f16*)(ws + 54525952);
  f16* kb   = (f16*)(ws + 88080384);
  f16* vtb  = (f16*)(ws + 96468992);
  f16* attn = (f16*)(ws + 104857600);  // needs ws_size >= 138412032

  cast_all<<<26624, 256, 0, stream>>>(x, Wq, Wk, Wv, Wo, x_h, w_h, wo_h);
  gemm_k<1><<<dim3(32, 24), 512, 0, stream>>>(x_h, w_h, qb, kb, vtb, nullptr);
  attn_kernel<<<dim3(2, 16, 16), 512, 0, stream>>>(qb, kb, vtb, attn);
  gemm_k<0><<<dim3(32, 16), 512, 0, stream>>>(attn, wo_h, nullptr, nullptr, nullptr, out);
}

// Round 4
// 385.634 us; speedup vs baseline: 1.3455x; 1.3455x over previous
//
#include <hip/hip_runtime.h>
#include <stdint.h>

// Problem: B=16, S=512, H=2048, NH=16, NKV=4, HD=128
// out = Wo-proj( softmax(rope(q) @ rope(k)^T * hd^-.5) @ v )  with GQA rep=4
//
// ws layout (f16 intermediates):
//   x_h   [8192,2048]        @ 0
//   w_h   [3072,2048]        @ 33554432  (Wq 0..2047, Wk 2048..2559, Wv 2560..3071)
//   wo_h  [2048,2048]        @ 46137344
//   q     [16,16,512,128]    @ 54525952   (RoPE fused in gemm epilogue)
//   k     [16,4,512,128]     @ 88080384   (RoPE fused)
//   vt    [16,4,128,512]     @ 96468992   (V transposed)
//   attn  [8192,2048]        @ 104857600

typedef _Float16 f16;
typedef _Float16 f16x4 __attribute__((ext_vector_type(4)));
typedef _Float16 f16x8 __attribute__((ext_vector_type(8)));
typedef float f32x4 __attribute__((ext_vector_type(4)));

#define B_   16
#define S_   512
#define H_   2048
#define NH_  16
#define NKV_ 4
#define HD_  128
#define ATT_SCALE 0.08838834764831843f
#define LOG2_10000_DIV64 0.20762050593045952f

#define AS1 __attribute__((address_space(1)))
#define AS3 __attribute__((address_space(3)))

// async global->LDS, 16B/lane. LDS dest must be wave-uniform; HW adds lane*16.
__device__ __forceinline__ void async16(const void* g, const void* l) {
  __builtin_amdgcn_global_load_lds((const AS1 unsigned int*)(uintptr_t)g,
                                   (AS3 unsigned int*)(uintptr_t)l, 16, 0, 0);
}

// ---------------- fused fp32 -> f16 cast for all 5 inputs ----------------
__global__ __launch_bounds__(256) void cast_all(const float* __restrict__ x,
                                                const float* __restrict__ wq,
                                                const float* __restrict__ wk,
                                                const float* __restrict__ wv,
                                                const float* __restrict__ wo,
                                                f16* __restrict__ x_h,
                                                f16* __restrict__ w_h,
                                                f16* __restrict__ wo_h) {
  const int i = blockIdx.x * 256 + threadIdx.x;
  const float4* src;
  f16x4* dst;
  if (i < 4194304) {                 // x: 8192*2048
    src = (const float4*)x + i;            dst = (f16x4*)x_h + i;
  } else if (i < 5242880) {          // Wq: 2048*2048
    int j = i - 4194304;
    src = (const float4*)wq + j;           dst = (f16x4*)w_h + j;
  } else if (i < 5505024) {          // Wk: 512*2048
    int j = i - 5242880;
    src = (const float4*)wk + j;           dst = (f16x4*)w_h + 1048576 + j;
  } else if (i < 5767168) {          // Wv: 512*2048
    int j = i - 5505024;
    src = (const float4*)wv + j;           dst = (f16x4*)w_h + 1310720 + j;
  } else {                           // Wo: 2048*2048
    int j = i - 5767168;
    src = (const float4*)wo + j;           dst = (f16x4*)wo_h + j;
  }
  float4 v = *src;
  f16x4 o = {(f16)v.x, (f16)v.y, (f16)v.z, (f16)v.w};
  *dst = o;
}

// ---------------- 256x128 GEMM, BK=64, 8 waves, 3-deep LDS ring ----------
// (unchanged: ring-3, counted vmcnt, swizzled frag reads; 42.6% MfmaUtil)
template<int MODE>
__global__ __launch_bounds__(512, 2) void gemm_k(const f16* __restrict__ A,
                                                 const f16* __restrict__ W,
                                                 f16* __restrict__ qo,
                                                 f16* __restrict__ ko,
                                                 f16* __restrict__ vto,
                                                 float* __restrict__ fout) {
  __shared__ __align__(16) f16 As[3][256 * 64];   // 3 x 32 KiB
  __shared__ __align__(16) f16 Bs[3][128 * 64];   // 3 x 16 KiB  (total 144 KiB)
  const int K = 2048;
  const int NT = 32;                       // K / 64
  const int m0 = blockIdx.x * 256;
  const int n0 = blockIdx.y * 128;
  const int tid = threadIdx.x;
  const int wave = tid >> 6, lane = tid & 63;
  const int quad = lane >> 4, l15 = lane & 15;
  const int wm = wave >> 1, wn = wave & 1;  // 4M x 2N, 64x64 per wave

  const f16* aptr[4];
  const f16* bptr[2];
#pragma unroll
  for (int i = 0; i < 4; ++i) {
    const int L = i * 512 + wave * 64 + lane;
    const int r = L >> 3, s = L & 7;
    aptr[i] = A + (size_t)(m0 + r) * K + (s ^ (r & 7)) * 8;
  }
#pragma unroll
  for (int i = 0; i < 2; ++i) {
    const int L = i * 512 + wave * 64 + lane;
    const int r = L >> 3, s = L & 7;
    bptr[i] = W + (size_t)(n0 + r) * K + (s ^ (r & 7)) * 8;
  }
  const int ldsw = wave * 1024;            // wave's chunk-group byte base

  f32x4 acc[4][4] = {};
  f16x8 aC[4], bC[4], aN[4], bN[4];

  auto ldA = [&](f16x8* d, const f16* base, int ks) {
#pragma unroll
    for (int mi = 0; mi < 4; ++mi) {
      const int row = wm * 64 + mi * 16 + l15;
      const int slot = (ks * 4 + quad) ^ (l15 & 7);
      d[mi] = *reinterpret_cast<const f16x8*>(base + row * 64 + slot * 8);
    }
  };
  auto ldB = [&](f16x8* d, const f16* base, int ks) {
#pragma unroll
    for (int ni = 0; ni < 4; ++ni) {
      const int col = wn * 32 + (ni >> 1) * 64 + (ni & 1) * 16 + l15;
      const int slot = (ks * 4 + quad) ^ (l15 & 7);
      d[ni] = *reinterpret_cast<const f16x8*>(base + col * 64 + slot * 8);
    }
  };
  auto mfma16 = [&](const f16x8* Af, const f16x8* Bf) {
#pragma unroll
    for (int mi = 0; mi < 4; ++mi)
#pragma unroll
      for (int ni = 0; ni < 4; ++ni)
        acc[mi][ni] = __builtin_amdgcn_mfma_f32_16x16x32_f16(Af[mi], Bf[ni], acc[mi][ni], 0, 0, 0);
  };

  // prologue: stage tiles 0,1 (12 loads/thread)
#pragma unroll
  for (int t = 0; t < 2; ++t) {
#pragma unroll
    for (int i = 0; i < 4; ++i)
      async16(aptr[i] + t * 64, (const char*)&As[t][0] + i * 8192 + ldsw);
#pragma unroll
    for (int i = 0; i < 2; ++i)
      async16(bptr[i] + t * 64, (const char*)&Bs[t][0] + i * 8192 + ldsw);
  }
  asm volatile("s_waitcnt vmcnt(6)" ::: "memory");  // tile 0 landed
  __builtin_amdgcn_s_barrier();
  ldA(aC, &As[0][0], 0);
  ldB(bC, &Bs[0][0], 0);

  for (int t = 0; t < NT; ++t) {
    const int buf = t % 3, bufn = (t + 1) % 3, bufs = (t + 2) % 3;
    const int sk = (t + 2) * 64;

    // ---- P0: MFMA ks=0 while ks=1 reads + 3 stage loads are in flight ----
    ldA(aN, &As[buf][0], 1);
    ldB(bN, &Bs[buf][0], 1);
    if (t + 2 < NT) {
      async16(aptr[0] + sk, (const char*)&As[bufs][0] + 0 * 8192 + ldsw);
      async16(aptr[1] + sk, (const char*)&As[bufs][0] + 1 * 8192 + ldsw);
      async16(bptr[0] + sk, (const char*)&Bs[bufs][0] + 0 * 8192 + ldsw);
    }
    asm volatile("s_waitcnt lgkmcnt(8)" ::: "memory");  // aC/bC ready
    __builtin_amdgcn_sched_barrier(0);
    __builtin_amdgcn_s_setprio(1);
    mfma16(aC, bC);
    __builtin_amdgcn_s_setprio(0);

    // ---- MID: tile t+1 resident (counted vmcnt, all waves) ----
    if (t + 1 < NT) {
      if (t + 2 < NT) asm volatile("s_waitcnt vmcnt(3)" ::: "memory");
      else            asm volatile("s_waitcnt vmcnt(0)" ::: "memory");
      __builtin_amdgcn_s_barrier();
    }

    // ---- P1: MFMA ks=1 while next-tile ks=0 reads + 3 stages in flight ----
    if (t + 1 < NT) {
      ldA(aC, &As[bufn][0], 0);
      ldB(bC, &Bs[bufn][0], 0);
    }
    if (t + 2 < NT) {
      async16(aptr[2] + sk, (const char*)&As[bufs][0] + 2 * 8192 + ldsw);
      async16(aptr[3] + sk, (const char*)&As[bufs][0] + 3 * 8192 + ldsw);
      async16(bptr[1] + sk, (const char*)&Bs[bufs][0] + 1 * 8192 + ldsw);
    }
    if (t + 1 < NT) asm volatile("s_waitcnt lgkmcnt(8)" ::: "memory");
    else            asm volatile("s_waitcnt lgkmcnt(0)" ::: "memory");
    __builtin_amdgcn_sched_barrier(0);
    __builtin_amdgcn_s_setprio(1);
    mfma16(aN, bN);
    __builtin_amdgcn_s_setprio(0);
    if (t + 1 < NT) __builtin_amdgcn_s_barrier();
  }

  // ---------------- epilogues ----------------
  if constexpr (MODE == 1) {
    const int b_ = m0 >> 9;  // batch (uniform per block; 256 | 512)
    if (n0 >= 2560) {
      // ---- V: no rope, store transposed [b, kh, d, s] ----
      const int h = (n0 - 2560) >> 7;
      f16* vb = vto + ((size_t)b_ * NKV_ + h) * HD_ * S_;
#pragma unroll
      for (int mi = 0; mi < 4; ++mi)
#pragma unroll
        for (int r = 0; r < 4; ++r) {
          const int s = (m0 + wm * 64 + mi * 16 + quad * 4 + r) & 511;
#pragma unroll
          for (int ni = 0; ni < 4; ++ni) {
            const int d = (ni >> 1) * 64 + wn * 32 + (ni & 1) * 16 + l15;
            vb[(size_t)d * S_ + s] = (f16)acc[mi][ni][r];
          }
        }
    } else {
      // ---- Q or K: fused RoPE, store [b, h, s, d] ----
      f16* ob = (n0 < 2048)
          ? (qo + ((size_t)b_ * NH_ + (n0 >> 7)) * S_ * HD_)
          : (ko + ((size_t)b_ * NKV_ + ((n0 - 2048) >> 7)) * S_ * HD_);
      float invf[2];
#pragma unroll
      for (int ni = 0; ni < 2; ++ni)
        invf[ni] = exp2f((float)(wn * 32 + ni * 16 + l15) * -LOG2_10000_DIV64);
#pragma unroll
      for (int mi = 0; mi < 4; ++mi)
#pragma unroll
        for (int r = 0; r < 4; ++r) {
          const int s = (m0 + wm * 64 + mi * 16 + quad * 4 + r) & 511;
          const size_t rb = (size_t)s * HD_;
#pragma unroll
          for (int ni = 0; ni < 2; ++ni) {
            const int d = wn * 32 + ni * 16 + l15;  // 0..63
            float sn, cs;
            __sincosf((float)s * invf[ni], &sn, &cs);
            const float x1 = acc[mi][ni][r], x2 = acc[mi][ni + 2][r];
            ob[rb + d] = (f16)(x1 * cs - x2 * sn);
            ob[rb + d + 64] = (f16)(x2 * cs + x1 * sn);
          }
        }
    }
  } else {
    // ---- fp32 output: out = attn @ Wo^T ----
#pragma unroll
    for (int mi = 0; mi < 4; ++mi)
#pragma unroll
      for (int ni = 0; ni < 4; ++ni) {
        const int ncol = n0 + wn * 32 + (ni >> 1) * 64 + (ni & 1) * 16 + l15;
#pragma unroll
        for (int r = 0; r < 4; ++r) {
          const int mrow = m0 + wm * 64 + mi * 16 + quad * 4 + r;
          fout[(size_t)mrow * 2048 + ncol] = acc[mi][ni][r];
        }
      }
  }
}

// ---------------- flash attention (v3, spill-fixed) ----------------
// 8 waves x 32 q-rows = 256 rows/block, grid (2,16,16)=512 blocks.
// KVBLK=64, K double-buffered in LDS, V single-buffered, Q in registers.
// NOTE: NO min-waves __launch_bounds__ clause. Round-3's (512,4) capped the
// allocator at 64 VGPRs for a ~140-VGPR kernel -> O/aq spilled to scratch
// -> 660 MB of HBM spill traffic (FETCH 533/WRITE 321 MB vs 160/32 static).
// Let the allocator take what it needs; 12 waves/CU is plenty here.
__global__ __launch_bounds__(512) void attn_kernel(const f16* __restrict__ q,
                                                   const f16* __restrict__ k,
                                                   const f16* __restrict__ vt,
                                                   f16* __restrict__ out) {
  __shared__ __align__(16) f16 Kb[2][64 * 128];   // [key][d], chunk c^(r&15)
  __shared__ __align__(16) f16 Vb[128 * 64];      // [d][key], chunk c^(r&7)
  __shared__ __align__(16) f16 Ps[8][32 * 64];    // per-wave P, chunk c^(r&7)

  const int qt = blockIdx.x, h = blockIdx.y, b = blockIdx.z;
  const int kvh = h >> 2;
  const int tid = threadIdx.x;
  const int wave = tid >> 6, lane = tid & 63;
  const int quad = lane >> 4, l15 = lane & 15;

  const f16* qbase = q + (((size_t)b * NH_ + h) * S_ + qt * 256) * HD_;
  const f16* kbase = k + ((size_t)b * NKV_ + kvh) * S_ * HD_;
  const f16* vbase = vt + ((size_t)b * NKV_ + kvh) * HD_ * S_;

  auto stageK = [&](int j) {
    f16* dst = &Kb[j & 1][0];
#pragma unroll
    for (int i = 0; i < 2; ++i) {
      const int L0 = i * 512 + wave * 64;          // wave-uniform base chunk
      const int L = L0 + lane;
      const int r = L >> 4, c = L & 15;
      async16(kbase + (size_t)(j * 64 + r) * HD_ + (c ^ (r & 15)) * 8,
              (const char*)dst + (size_t)L0 * 16);
    }
  };
  auto stageV = [&](int j) {
#pragma unroll
    for (int i = 0; i < 2; ++i) {
      const int L0 = i * 512 + wave * 64;
      const int L = L0 + lane;
      const int r = L >> 3, c = L & 7;
      async16(vbase + (size_t)r * S_ + j * 64 + (c ^ (r & 7)) * 8,
              (const char*)&Vb[0] + (size_t)L0 * 16);
    }
  };

  // Q fragments straight to registers (read exactly once, union covers tile)
  f16x8 aq[2][4];
#pragma unroll
  for (int mi = 0; mi < 2; ++mi)
#pragma unroll
    for (int ks = 0; ks < 4; ++ks)
      aq[mi][ks] = *reinterpret_cast<const f16x8*>(
          qbase + (size_t)(wave * 32 + mi * 16 + l15) * HD_ + ks * 32 + quad * 8);

  stageK(0);

  f32x4 O[2][8] = {};
  float mrun[2][4], lrun[2][4];
#pragma unroll
  for (int mi = 0; mi < 2; ++mi)
#pragma unroll
    for (int r = 0; r < 4; ++r) { mrun[mi][r] = -3.0e38f; lrun[mi][r] = 0.f; }

  for (int j = 0; j < 8; ++j) {
    // K[j] is the only outstanding group (plus aq at j=0): drain own, then
    // barrier -> every wave's staging portion visible to all.
    asm volatile("s_waitcnt vmcnt(0)" ::: "memory");
    __builtin_amdgcn_s_barrier();           // also: all waves done PV[j-1]
    stageV(j);                               // hides under QK^T + softmax

    // ---- S = Q K^T for 32 q-rows x 64 keys ----
    f32x4 Sc[2][4] = {};
#pragma unroll
    for (int ks = 0; ks < 4; ++ks) {
      f16x8 bk[4];
#pragma unroll
      for (int ni = 0; ni < 4; ++ni) {
        const int row = ni * 16 + l15;
        bk[ni] = *reinterpret_cast<const f16x8*>(
            &Kb[j & 1][row * 128 + (((ks * 4 + quad) ^ l15) & 15) * 8]);
      }
#pragma unroll
      for (int mi = 0; mi < 2; ++mi)
#pragma unroll
        for (int ni = 0; ni < 4; ++ni)
          Sc[mi][ni] = __builtin_amdgcn_mfma_f32_16x16x32_f16(aq[mi][ks], bk[ni], Sc[mi][ni], 0, 0, 0);
    }

    // ---- online softmax (row = mi*16 + quad*4 + r, col = ni*16 + l15) ----
#pragma unroll
    for (int mi = 0; mi < 2; ++mi)
#pragma unroll
      for (int r = 0; r < 4; ++r) {
        float mx = fmaxf(fmaxf(Sc[mi][0][r], Sc[mi][1][r]),
                         fmaxf(Sc[mi][2][r], Sc[mi][3][r]));
        mx *= ATT_SCALE;
#pragma unroll
        for (int off = 1; off < 16; off <<= 1) mx = fmaxf(mx, __shfl_xor(mx, off));
        const float mnew = fmaxf(mrun[mi][r], mx);
        const float alpha = __expf(mrun[mi][r] - mnew);
        float rs = 0.f;
#pragma unroll
        for (int ni = 0; ni < 4; ++ni) {
          const float pv = __expf(Sc[mi][ni][r] * ATT_SCALE - mnew);
          Sc[mi][ni][r] = pv;
          rs += pv;
        }
#pragma unroll
        for (int off = 1; off < 16; off <<= 1) rs += __shfl_xor(rs, off);
        lrun[mi][r] = lrun[mi][r] * alpha + rs;
        mrun[mi][r] = mnew;
#pragma unroll
        for (int ni = 0; ni < 8; ++ni) O[mi][ni][r] *= alpha;
        const int rowl = mi * 16 + quad * 4 + r;
#pragma unroll
        for (int ni = 0; ni < 4; ++ni) {
          const int col = ni * 16 + l15;
          Ps[wave][rowl * 64 + (((ni * 2 + (l15 >> 3)) ^ (rowl & 7)) << 3) + (l15 & 7)] =
              (f16)Sc[mi][ni][r];
        }
      }

    // V[j] landed? (K[j+1] not yet issued -> vmcnt(0) is exact & cheap here)
    asm volatile("s_waitcnt vmcnt(0)" ::: "memory");
    __builtin_amdgcn_s_barrier();           // Vb visible to all waves
    if (j < 7) stageK(j + 1);                // hides under PV + next QK^T

    // ---- O += P V (ks-outer, ni-inner: each bv read once, shared by mi) ----
#pragma unroll
    for (int ks = 0; ks < 2; ++ks) {
      f16x8 ap[2];
#pragma unroll
      for (int mi = 0; mi < 2; ++mi) {
        const int rowl = mi * 16 + l15;
        ap[mi] = *reinterpret_cast<const f16x8*>(
            &Ps[wave][rowl * 64 + (((ks * 4 + quad) ^ (l15 & 7)) << 3)]);
      }
#pragma unroll
      for (int ni = 0; ni < 8; ++ni) {
        const int row = ni * 16 + l15;
        const f16x8 bv = *reinterpret_cast<const f16x8*>(
            &Vb[row * 64 + (((ks * 4 + quad) ^ (l15 & 7)) << 3)]);
#pragma unroll
        for (int mi = 0; mi < 2; ++mi)
          O[mi][ni] = __builtin_amdgcn_mfma_f32_16x16x32_f16(ap[mi], bv, O[mi][ni], 0, 0, 0);
      }
    }
  }

  // epilogue: normalize, write attn[b, s, h*128 + d]
#pragma unroll
  for (int mi = 0; mi < 2; ++mi)
#pragma unroll
    for (int r = 0; r < 4; ++r) {
      const float inv = 1.f / lrun[mi][r];
      const int srow = qt * 256 + wave * 32 + mi * 16 + quad * 4 + r;
#pragma unroll
      for (int ni = 0; ni < 8; ++ni)
        out[((size_t)b * S_ + srow) * H_ + h * HD_ + ni * 16 + l15] = (f16)(O[mi][ni][r] * inv);
    }
}

extern "C" void kernel_launch(void* const* d_in, const int* in_sizes, int n_in,
                              void* d_out, int out_size, void* d_ws, size_t ws_size,
                              hipStream_t stream) {
  const float* x = (const float*)d_in[0];
  const float* Wq = (const float*)d_in[1];
  const float* Wk = (const float*)d_in[2];
  const float* Wv = (const float*)d_in[3];
  const float* Wo = (const float*)d_in[4];
  float* out = (float*)d_out;
  char* ws = (char*)d_ws;

  f16* x_h  = (f16*)(ws + 0);
  f16* w_h  = (f16*)(ws + 33554432);
  f16* wo_h = (f16*)(ws + 46137344);
  f16* qb   = (f16*)(ws + 54525952);
  f16* kb   = (f16*)(ws + 88080384);
  f16* vtb  = (f16*)(ws + 96468992);
  f16* attn = (f16*)(ws + 104857600);  // needs ws_size >= 138412032

  cast_all<<<26624, 256, 0, stream>>>(x, Wq, Wk, Wv, Wo, x_h, w_h, wo_h);
  gemm_k<1><<<dim3(32, 24), 512, 0, stream>>>(x_h, w_h, qb, kb, vtb, nullptr);
  attn_kernel<<<dim3(2, 16, 16), 512, 0, stream>>>(qb, kb, vtb, attn);
  gemm_k<0><<<dim3(32, 16), 512, 0, stream>>>(attn, wo_h, nullptr, nullptr, nullptr, out);
}